// Round 9
// baseline (157.308 us; speedup 1.0000x reference)
//
#include <hip/hip_runtime.h>
#include <hip/hip_bf16.h>
#include <math.h>

#define B_    4
#define CIN   128
#define L_    16384
#define NH    4
#define NN    32
#define MT    528
#define CP    2112
#define DIM_  64
#define LT    64
#define MID   8192
#define EPS_  1e-5f

// padded-K layout (R3/R7-proven): per head 80 k-blocks of 8; heads contiguous in K.
#define KPH   640
#define KTOT  2560
#define WSWN  (KTOT * DIM_)       // 163840 bf16 slots
#define FSWN  (2 * 4 * 64 * 8)    // 4096 bf16 slots
#define LOGITS_BLOCKS 1024
#define PREP_BLOCKS   656         // (WSWN+FSWN)/256

typedef __attribute__((ext_vector_type(8))) short short8;
typedef __attribute__((ext_vector_type(4))) float float4v;

__device__ inline unsigned short f2bf(float f) {
  unsigned u = __float_as_uint(f);
  unsigned r = (u + 0x7fffu + ((u >> 16) & 1u)) >> 16;
  return (unsigned short)r;
}
__device__ inline float bf2f(unsigned short h) {
  return __uint_as_float(((unsigned)h) << 16);
}
// pack two f32 -> two bf16 (round-half-away) in one dword via v_perm
__device__ inline unsigned pack2bf(float a, float b) {
  return __builtin_amdgcn_perm(__float_as_uint(b) + 0x8000u,
                               __float_as_uint(a) + 0x8000u, 0x07060302u);
}

// decode head-local k-block (0..79) -> (i, jb)
__device__ inline void kb_decode(int id, int& i, int& jb) {
  if (id < 32)      { i = id >> 2;               jb = id & 3; }
  else if (id < 56) { int r = id - 32; int d = r / 3; i = 8 + d;  jb = 1 + (r - 3 * d); }
  else if (id < 72) { int r = id - 56; i = 16 + (r >> 1); jb = 2 + (r & 1); }
  else              { i = 24 + (id - 72);         jb = 3; }
}

// ---------------- kernel 1: logits (closed-form) ∪ weight-swizzle prep (R7 verbatim) ----------------
__global__ __launch_bounds__(256) void k_pre(const float* __restrict__ dr_w,
                                             const float* __restrict__ fc1_w,
                                             const float* __restrict__ x,
                                             const float* __restrict__ g1,
                                             const float* __restrict__ b1,
                                             unsigned short* __restrict__ wsw,
                                             unsigned short* __restrict__ fsw,
                                             float* __restrict__ ws_a,
                                             float* __restrict__ ws_bsum) {
  if (blockIdx.x >= LOGITS_BLOCKS) {
    int s = (blockIdx.x - LOGITS_BLOCKS) * 256 + threadIdx.x;
    if (s < WSWN) {
      int j    = s & 7;
      int lane = (s >> 3) & 63;
      int ot   = (s >> 9) & 3;
      int ksg  = s >> 11;
      int o  = ot * 16 + (lane & 15);
      int kp = ksg * 32 + (lane >> 4) * 8 + j;   // padded-K index 0..2559
      int h  = kp / KPH;
      int kk = kp - h * KPH;
      int kb = kk >> 3, jo = kk & 7;
      int i, jb; kb_decode(kb, i, jb);
      int jch = jb * 8 + jo;
      float val = 0.f;
      if (jch >= i) {
        int fi = 32 * i - (i * (i - 1)) / 2;
        int m  = h * MT + fi + (jch - i);
        val = dr_w[(size_t)o * CP + m];
      }
      wsw[s] = f2bf(val);
    } else {
      int s2 = s - WSWN;
      int j    = s2 & 7;
      int lane = (s2 >> 3) & 63;
      int ot   = (s2 >> 9) & 3;
      int ks2  = s2 >> 11;
      int o = ot * 16 + (lane & 15);
      int c = ks2 * 32 + (lane >> 4) * 8 + j;
      fsw[s2] = f2bf(fc1_w[o * DIM_ + c]);
    }
    return;
  }
  // ---- logits path (R7-proven) ----
  int blk = blockIdx.x;
  int b = blk >> 8;
  int l0 = (blk & 255) << 6;
  int t = threadIdx.x;
  int l = t & 63, q = t >> 6;
  __shared__ float xs[CIN], smid[CIN];
  __shared__ float part[4][64], part2[4][64], mu_s[64], isd_s[64];
  __shared__ float musd[2];

  if (t < CIN) xs[t] = x[(size_t)b * CIN * L_ + (size_t)t * L_ + MID];

  float tv[32];
  const float* xb = x + (size_t)b * CIN * L_ + l0 + l;
  float s = 0.f, s2 = 0.f;
#pragma unroll
  for (int cc = 0; cc < 32; cc++) {
    float v = xb[(size_t)(cc * 4 + q) * L_];
    tv[cc] = v; s += v; s2 += v * v;
  }
  part[q][l] = s; part2[q][l] = s2;
  __syncthreads();
  if (t == 0) {
    float su = 0.f;
    for (int c = 0; c < CIN; c++) su += xs[c];
    float mu = su / CIN;
    float sv = 0.f;
    for (int c = 0; c < CIN; c++) { float d = xs[c] - mu; sv += d * d; }
    musd[0] = mu; musd[1] = rsqrtf(sv / CIN + EPS_);
  }
  if (t < 64) {
    float su = part[0][t] + part[1][t] + part[2][t] + part[3][t];
    float su2 = part2[0][t] + part2[1][t] + part2[2][t] + part2[3][t];
    float mu = su * (1.f / CIN);
    float var = su2 * (1.f / CIN) - mu * mu;
    mu_s[t] = mu; isd_s[t] = rsqrtf(var + EPS_);
  }
  __syncthreads();
  if (t < CIN) {
    int c = ((t & 31) << 2) + (t >> 5);   // shuffled row -> orig channel
    smid[t] = (xs[c] - musd[0]) * musd[1] * g1[c] + b1[c];
  }
  {
    float mu = mu_s[l], isd = isd_s[l];
#pragma unroll
    for (int cc = 0; cc < 32; cc++) {
      int co = cc * 4 + q;
      tv[cc] = (tv[cc] - mu) * isd * g1[co] + b1[co];
    }
  }
  __syncthreads();
  float T2 = 0.f, T4 = 0.f, st = 0.f, sc2 = 0.f, S2 = 0.f, S4 = 0.f;
#pragma unroll
  for (int i = 0; i < 32; i++) {
    float si = smid[q * 32 + i];
    float ti = tv[i];
    float t2 = ti * ti;
    T2 += t2; T4 = fmaf(t2, t2, T4);
    float ci = si * ti;
    st += ci; sc2 = fmaf(ci, ci, sc2);
    float s2i = si * si;
    S2 += s2i; S4 = fmaf(s2i, s2i, S4);
  }
  float num = 0.5f * (st * st + sc2);
  float logit = num * rsqrtf(0.25f * (T2 * T2 + T4) * (S2 * S2 + S4));
  float e = expf(logit - 1.f);
  ws_a[((size_t)b * NH + q) * L_ + l0 + l] = e;
  float ws = e;
#pragma unroll
  for (int mk = 1; mk < 64; mk <<= 1) ws += __shfl_xor(ws, mk, 64);
  if (l == 0) ws_bsum[((size_t)b * NH + q) * 256 + (blk & 255)] = ws;
}

// ---------------- kernel 2: MFMA main (R7 structure; 4-bit xor swizzle; perm packing) ----------------
struct __align__(16) SmemM {
  union __align__(16) { unsigned short p2[4 * 5 * 4 * 16 * 8]; float zb[64 * 65]; } u1;
  union __align__(16) { unsigned short ut[64 * 128]; unsigned short zn2[4 * 2 * 4 * 16 * 8]; } u2;
  float part[4][64], part2[4][64], mu_s[64], isd_s[64];
};

// 4-bit xor swizzle: row l stride 128 shorts; 16B-block index (c>>3) ^ (l&15)
__device__ inline int utidx(int l, int c) {
  return l * 128 + ((((c >> 3) ^ (l & 15))) << 3) + (c & 7);
}

__global__ __launch_bounds__(256, 4) void k_main(const float* __restrict__ x,
      const float* __restrict__ g1, const float* __restrict__ b1,
      const float* __restrict__ dr_b,
      const float* __restrict__ g2, const float* __restrict__ b2,
      const float* __restrict__ fc1_b,
      const unsigned short* __restrict__ wsw, const unsigned short* __restrict__ fsw,
      const float* __restrict__ ws_a, const float* __restrict__ ws_bsum,
      float* __restrict__ out) {
  __shared__ SmemM sm;
  int blk = blockIdx.x;
  int b = blk >> 8;
  int l0 = (blk & 255) << 6;
  int t = threadIdx.x;
  int l = t & 63, q = t >> 6;   // q = wave id; l = lane

  // asum: parallel partial read + wave butterfly (deterministic)
  float asum;
  {
    const float* bs = ws_bsum + ((size_t)b * NH + q) * 256;
    float a0 = bs[l] + bs[l + 64] + bs[l + 128] + bs[l + 192];
#pragma unroll
    for (int mk = 1; mk < 64; mk <<= 1) a0 += __shfl_xor(a0, mk, 64);
    asum = a0;
  }
  float e = ws_a[((size_t)b * NH + q) * L_ + l0 + l];
  float sa = sqrtf(e * ((float)L_ / asum));

  const float* xb = x + (size_t)b * CIN * L_ + l0;
  float s = 0.f, s2 = 0.f;
#pragma unroll
  for (int cb = 0; cb < 4; cb++) {
    unsigned pk[4];
#pragma unroll
    for (int e2 = 0; e2 < 4; e2++) {
      int cc0 = cb * 8 + 2 * e2;
      float v0 = xb[(size_t)(cc0 * 4 + q) * L_ + l];
      float v1 = xb[(size_t)((cc0 + 1) * 4 + q) * L_ + l];
      s += v0 + v1; s2 += v0 * v0 + v1 * v1;
      pk[e2] = pack2bf(v0, v1);
    }
    *(short8*)&sm.u2.ut[l * 128 + (((q * 4 + cb) ^ (l & 15)) << 3)] = *(short8*)pk;
  }
  sm.part[q][l] = s; sm.part2[q][l] = s2;
  __syncthreads();
  if (t < 64) {
    float su = sm.part[0][t] + sm.part[1][t] + sm.part[2][t] + sm.part[3][t];
    float su2 = sm.part2[0][t] + sm.part2[1][t] + sm.part2[2][t] + sm.part2[3][t];
    float mu = su * (1.f / CIN);
    float var = su2 * (1.f / CIN) - mu * mu;
    sm.mu_s[t] = mu; sm.isd_s[t] = rsqrtf(var + EPS_);
  }
  __syncthreads();
  {
    float mu = sm.mu_s[l], isd = sm.isd_s[l];
#pragma unroll
    for (int cb = 0; cb < 4; cb++) {
      unsigned short* pp = &sm.u2.ut[l * 128 + (((q * 4 + cb) ^ (l & 15)) << 3)];
      short8 v8 = *(short8*)pp;
      unsigned pk[4];
#pragma unroll
      for (int e2 = 0; e2 < 4; e2++) {
        int cc0 = cb * 8 + 2 * e2;
        int co0 = cc0 * 4 + q, co1 = (cc0 + 1) * 4 + q;
        float t0 = ((bf2f((unsigned short)v8[2 * e2])     - mu) * isd * g1[co0] + b1[co0]) * sa;
        float t1 = ((bf2f((unsigned short)v8[2 * e2 + 1]) - mu) * isd * g1[co1] + b1[co1]) * sa;
        pk[e2] = pack2bf(t0, t1);
      }
      *(short8*)pp = *(short8*)pk;
    }
  }
  __syncthreads();

  float4v acc[4];
  acc[0] = (float4v)0.f; acc[1] = (float4v)0.f; acc[2] = (float4v)0.f; acc[3] = (float4v)0.f;
  int tl = l;
  int ltile = l >> 4, n = l & 15;

  for (int cc16 = 0; cc16 < 16; cc16++) {
    int h = cc16 >> 2;
    int cpart = cc16 & 3;
#pragma unroll
    for (int s5 = 0; s5 < 5; s5++) {
      int kbl = q * 5 + s5;            // 0..19
      int kbh = cpart * 20 + kbl;      // 0..79
      int i, jb; kb_decode(kbh, i, jb);
      float ui = bf2f(sm.u2.ut[utidx(l, h * 32 + i)]);
      short8 ub = *(short8*)&sm.u2.ut[l * 128 + (((h * 4 + jb) ^ (l & 15)) << 3)];
      unsigned pk[4];
#pragma unroll
      for (int e2 = 0; e2 < 4; e2++) {
        float p0 = ui * bf2f((unsigned short)ub[2 * e2]);
        float p1 = ui * bf2f((unsigned short)ub[2 * e2 + 1]);
        pk[e2] = pack2bf(p0, p1);
      }
      int ks = kbl >> 2, quad = kbl & 3;
      *(short8*)&sm.u1.p2[(((ltile * 5 + ks) * 4 + quad) * 16 + n) * 8] = *(short8*)pk;
    }
    __syncthreads();
    const unsigned short* wbase = wsw + (size_t)(cc16 * 5) * 2048 + tl * 8;
#pragma unroll
    for (int ks = 0; ks < 5; ks++) {
      short8 bf = *(short8*)&sm.u1.p2[((q * 5 + ks) * 64 + tl) * 8];
      const unsigned short* wk = wbase + ks * 2048;
      short8 a0 = *(const short8*)(wk);
      short8 a1 = *(const short8*)(wk + 512);
      short8 a2 = *(const short8*)(wk + 1024);
      short8 a3 = *(const short8*)(wk + 1536);
      acc[0] = __builtin_amdgcn_mfma_f32_16x16x32_bf16(a0, bf, acc[0], 0, 0, 0);
      acc[1] = __builtin_amdgcn_mfma_f32_16x16x32_bf16(a1, bf, acc[1], 0, 0, 0);
      acc[2] = __builtin_amdgcn_mfma_f32_16x16x32_bf16(a2, bf, acc[2], 0, 0, 0);
      acc[3] = __builtin_amdgcn_mfma_f32_16x16x32_bf16(a3, bf, acc[3], 0, 0, 0);
    }
    __syncthreads();
  }

  int quad = tl >> 4;
#pragma unroll
  for (int ot = 0; ot < 4; ot++) {
#pragma unroll
    for (int r = 0; r < 4; r++) {
      int o = ot * 16 + quad * 4 + r;
      sm.u1.zb[(q * 16 + n) * 65 + o] = acc[ot][r] + dr_b[o];
    }
  }
  __syncthreads();
  {
    float ss = 0.f, ss2 = 0.f;
#pragma unroll
    for (int k = 0; k < 16; k++) {
      float v = sm.u1.zb[l * 65 + q * 16 + k];
      ss += v; ss2 += v * v;
    }
    sm.part[q][l] = ss; sm.part2[q][l] = ss2;
  }
  __syncthreads();
  if (t < 64) {
    float su = sm.part[0][t] + sm.part[1][t] + sm.part[2][t] + sm.part[3][t];
    float su2 = sm.part2[0][t] + sm.part2[1][t] + sm.part2[2][t] + sm.part2[3][t];
    float mu = su * (1.f / DIM_);
    float var = su2 * (1.f / DIM_) - mu * mu;
    sm.mu_s[t] = mu; sm.isd_s[t] = rsqrtf(var + EPS_);
  }
  __syncthreads();
  {
    float mu2 = sm.mu_s[l], isd2 = sm.isd_s[l];
#pragma unroll
    for (int kk = 0; kk < 2; kk++) {
      int kb2 = q * 2 + kk;
      int c0 = kb2 * 8;
      unsigned pk[4];
#pragma unroll
      for (int e2 = 0; e2 < 4; e2++) {
        int ca = c0 + 2 * e2, cb2 = ca + 1;
        float va = (sm.u1.zb[l * 65 + ca] - mu2) * isd2 * g2[ca] + b2[ca];
        float vb = (sm.u1.zb[l * 65 + cb2] - mu2) * isd2 * g2[cb2] + b2[cb2];
        pk[e2] = pack2bf(va, vb);
      }
      int ks2 = kb2 >> 2, qd2 = kb2 & 3;
      *(short8*)&sm.u2.zn2[(((ltile * 2 + ks2) * 4 + qd2) * 16 + n) * 8] = *(short8*)pk;
    }
  }
  __syncthreads();
  float4v acc2[4];
  acc2[0] = (float4v)0.f; acc2[1] = (float4v)0.f; acc2[2] = (float4v)0.f; acc2[3] = (float4v)0.f;
#pragma unroll
  for (int ks2 = 0; ks2 < 2; ks2++) {
    short8 bz = *(short8*)&sm.u2.zn2[((q * 2 + ks2) * 64 + tl) * 8];
    const unsigned short* fk = fsw + ks2 * 2048 + tl * 8;
    short8 f0 = *(const short8*)(fk);
    short8 f1 = *(const short8*)(fk + 512);
    short8 f2 = *(const short8*)(fk + 1024);
    short8 f3 = *(const short8*)(fk + 1536);
    acc2[0] = __builtin_amdgcn_mfma_f32_16x16x32_bf16(f0, bz, acc2[0], 0, 0, 0);
    acc2[1] = __builtin_amdgcn_mfma_f32_16x16x32_bf16(f1, bz, acc2[1], 0, 0, 0);
    acc2[2] = __builtin_amdgcn_mfma_f32_16x16x32_bf16(f2, bz, acc2[2], 0, 0, 0);
    acc2[3] = __builtin_amdgcn_mfma_f32_16x16x32_bf16(f3, bz, acc2[3], 0, 0, 0);
  }
#pragma unroll
  for (int ot = 0; ot < 4; ot++) {
#pragma unroll
    for (int r = 0; r < 4; r++) {
      int o2 = ot * 16 + quad * 4 + r;
      float sv = acc2[ot][r] + fc1_b[o2];
      float g = 0.5f * sv * (1.f + erff(sv * 0.70710678118f));
      out[((size_t)b * DIM_ + o2) * L_ + l0 + q * 16 + n] = g;
    }
  }
}

extern "C" void kernel_launch(void* const* d_in, const int* in_sizes, int n_in,
                              void* d_out, int out_size, void* d_ws, size_t ws_size,
                              hipStream_t stream) {
  const float* x    = (const float*)d_in[0];
  const float* n1w  = (const float*)d_in[1];
  const float* n1b  = (const float*)d_in[2];
  const float* drw  = (const float*)d_in[3];
  const float* drb  = (const float*)d_in[4];
  const float* n2w  = (const float*)d_in[5];
  const float* n2b  = (const float*)d_in[6];
  const float* fc1w = (const float*)d_in[7];
  const float* fc1b = (const float*)d_in[8];
  float* out = (float*)d_out;
  float* ws = (float*)d_ws;
  float* ws_a    = ws;                                  // 4*4*16384 floats
  float* ws_bsum = ws_a + (size_t)B_ * NH * L_;         // 16*256 floats
  unsigned short* wsw = (unsigned short*)(ws_bsum + B_ * NH * 256); // 163840 bf16
  unsigned short* fsw = wsw + WSWN;                     // 4096 bf16

  hipLaunchKernelGGL(k_pre, dim3(LOGITS_BLOCKS + PREP_BLOCKS), dim3(256), 0, stream,
                     drw, fc1w, x, n1w, n1b, wsw, fsw, ws_a, ws_bsum);
  hipLaunchKernelGGL(k_main, dim3(B_ * (L_ / LT)), dim3(256), 0, stream,
                     x, n1w, n1b, drb, n2w, n2b, fc1b, wsw, fsw, ws_a, ws_bsum, out);
}